// Round 4
// baseline (357.285 us; speedup 1.0000x reference)
//
#include <hip/hip_runtime.h>
#include <hip/hip_bf16.h>

#define NN 1024
#define IN_CH 128
#define EDGE_CH 32
#define OUT_CH 128

typedef __attribute__((ext_vector_type(8))) short bf16x8;
typedef __attribute__((ext_vector_type(4))) float f32x4;

// round-to-nearest-even float -> bf16 (bit trick)
static __device__ __forceinline__ short f2bf(float f) {
    union { float f; unsigned u; } v; v.f = f;
    unsigned r = v.u + 0x7FFFu + ((v.u >> 16) & 1u);
    return (short)(r >> 16);
}

// ---------------------------------------------------------------------------
// Kernel A: P = node_mat @ node_weight (stored TRANSPOSED, bf16: PT[o][m]),
//           R = node_mat @ root (fp32).  (unchanged)
// ---------------------------------------------------------------------------
__global__ void node_gemm_kernel(const float* __restrict__ node_mat,
                                 const float* __restrict__ node_weight,
                                 const float* __restrict__ root,
                                 short* __restrict__ PT,
                                 float* __restrict__ R) {
    __shared__ float nm[2 * IN_CH];
    int tid = threadIdx.x;
    int n0 = blockIdx.x * 2;
    nm[tid] = node_mat[n0 * IN_CH + tid];
    __syncthreads();
    int o = tid & 127;
    int h = tid >> 7;
    const float* nr = &nm[h * IN_CH];
    float accp = 0.f, accr = 0.f;
#pragma unroll 8
    for (int c = 0; c < IN_CH; ++c) {
        float x = nr[c];
        accp += x * node_weight[c * OUT_CH + o];
        accr += x * root[c * OUT_CH + o];
    }
    R[(size_t)(n0 + h) * OUT_CH + o] = accr;
    PT[(size_t)o * NN + (n0 + h)] = f2bf(accp);  // transposed bf16 store
}

// ---------------------------------------------------------------------------
// Kernel B v3 (heavy): per node n,
//   G[b]   = sum_m adj[n,m] * relu( sum_e edge_adj[e,n,m] * L1[e,b] )
//   out[n,o] = sum_{b<127} G[b]*L2[b,o] + R[n,o] + bias[o]
//
// v2 post-mortem: 83 us @ 1.0 TB/s, MfmaUtil 3.8%, VALUBusy 17% -> LATENCY
// bound. 4-wave lockstep (__syncthreads per chunk) + 1-deep prefetch meant
// ~3 independent memory streams per CU and ~600cy exposed HBM latency per
// chunk. v3: WAVE-INDEPENDENT staging, no barriers in the main loop.
//   - wave w owns m in [w*256, w*256+256), 8 chunks of 32 m.
//   - per-wave LDS double buffer [32 m][40 shorts] (80-B rows, 16B-aligned
//     b128 reads). Intra-wave transpose: LDS ops are in-order per wave; only
//     compiler reordering must be fenced -> __builtin_amdgcn_wave_barrier().
//   - 2-deep prefetch: issue chunk c+2, compute chunk c, convert chunk c+1.
//   - staging loads: instr i covers e = i*8+(lane>>3), m = (lane&7)*4:
//     8 consecutive float4 per e-row = full 128-B lines, 8 rows/instr.
// MFMA 16x16x32 bf16, K=32=EDGE_CH. A-frag lane=(quad,col): A[row=col][k=8q+j]
// = L1^T; B-frag: B[k=8q+j][col=m]; D: row=quad*4+r (b), col = m-lane.
// ---------------------------------------------------------------------------
__global__ void edge_out_kernel(const float* __restrict__ edge_adj,
                                const float* __restrict__ adj,
                                const float* __restrict__ L1,
                                const float* __restrict__ L2,
                                const float* __restrict__ R,
                                const float* __restrict__ bias,
                                float* __restrict__ out) {
    int n = blockIdx.x;
    int tid = threadIdx.x;
    int wave = tid >> 6;
    int lane = tid & 63;
    int quad = lane >> 4;
    int col  = lane & 15;

    // per-wave double-buffered transposed chunk: [32 m][40 shorts] = 2560 B
    __shared__ __attribute__((aligned(16))) short ea_lds[4][2][32 * 40];  // 20 KB
    __shared__ float gred[4][OUT_CH];
    __shared__ float gs[OUT_CH];
    __shared__ float part[2][OUT_CH];

    // Preload constant A fragments: 8 b-tiles of L1^T [b=bt*16+col][e=quad*8+j]
    bf16x8 a_frag[8];
#pragma unroll
    for (int bt = 0; bt < 8; ++bt) {
        int b = bt * 16 + col;
#pragma unroll
        for (int j = 0; j < 8; ++j) {
            int e = quad * 8 + j;
            float v = (b < OUT_CH - 1) ? L1[e * (OUT_CH - 1) + b] : 0.0f;  // pad b=127
            a_frag[bt][j] = f2bf(v);
        }
    }

    float g_acc[8][4];
#pragma unroll
    for (int bt = 0; bt < 8; ++bt)
#pragma unroll
        for (int r = 0; r < 4; ++r) g_acc[bt][r] = 0.0f;

    const float* adj_row = adj + (size_t)n * NN;
    int mw = wave * 256;                 // wave's m-base
    int eg = lane >> 3;                  // 0..7 (e sub-index)
    int ml = (lane & 7) * 4;             // 0..28 (m within chunk)
    const float* ea_nm = edge_adj + (size_t)n * NN + mw + ml;  // + e*NN*NN + c*32

    short* buf0 = &ea_lds[wave][0][0];
    short* buf1 = &ea_lds[wave][1][0];

    // prologue: issue chunks 0 and 1, convert chunk 0 into buf0
    f32x4 st[2][4];
#pragma unroll
    for (int i = 0; i < 4; ++i)
        st[0][i] = *(const f32x4*)(ea_nm + (size_t)(i * 8 + eg) * (size_t)(NN * NN));
#pragma unroll
    for (int i = 0; i < 4; ++i)
        st[1][i] = *(const f32x4*)(ea_nm + (size_t)(i * 8 + eg) * (size_t)(NN * NN) + 32);
#pragma unroll
    for (int i = 0; i < 4; ++i)
#pragma unroll
        for (int k = 0; k < 4; ++k)
            buf0[(ml + k) * 40 + i * 8 + eg] = f2bf(st[0][i][k]);
    __builtin_amdgcn_wave_barrier();

#pragma unroll
    for (int c = 0; c < 8; ++c) {
        const int cur = c & 1;
        short* bufc = (cur == 0) ? buf0 : buf1;
        short* bufn = (cur == 0) ? buf1 : buf0;
        // issue chunk c+2 into st[cur] (registers freed by iter c-1's convert)
        if (c < 6) {
#pragma unroll
            for (int i = 0; i < 4; ++i)
                st[cur][i] = *(const f32x4*)(ea_nm +
                    (size_t)(i * 8 + eg) * (size_t)(NN * NN) + (c + 2) * 32);
        }
        // compute chunk c from bufc: 2 subtiles of 16 m
#pragma unroll
        for (int s = 0; s < 2; ++s) {
            int mloc = s * 16 + col;
            float adjv = adj_row[mw + c * 32 + mloc];
            bf16x8 bf = *(const bf16x8*)(bufc + mloc * 40 + quad * 8);
#pragma unroll
            for (int bt = 0; bt < 8; ++bt) {
                f32x4 d = __builtin_amdgcn_mfma_f32_16x16x32_bf16(
                    a_frag[bt], bf, (f32x4){0.f, 0.f, 0.f, 0.f}, 0, 0, 0);
#pragma unroll
                for (int r = 0; r < 4; ++r)
                    g_acc[bt][r] += fmaxf(d[r], 0.0f) * adjv;
            }
        }
        // convert chunk c+1 (st[cur^1]) into bufn
        if (c < 7) {
            __builtin_amdgcn_wave_barrier();  // bufn reads (iter c-1) before writes
#pragma unroll
            for (int i = 0; i < 4; ++i)
#pragma unroll
                for (int k = 0; k < 4; ++k)
                    bufn[(ml + k) * 40 + i * 8 + eg] = f2bf(st[cur ^ 1][i][k]);
            __builtin_amdgcn_wave_barrier();  // writes before iter c+1 reads
        }
    }

    // reduce over the 16 column-lanes of each quad (sum over this lane's m's)
#pragma unroll
    for (int bt = 0; bt < 8; ++bt)
#pragma unroll
        for (int r = 0; r < 4; ++r) {
            float v = g_acc[bt][r];
            v += __shfl_xor(v, 1);
            v += __shfl_xor(v, 2);
            v += __shfl_xor(v, 4);
            v += __shfl_xor(v, 8);
            g_acc[bt][r] = v;
        }

    if (col == 0) {
#pragma unroll
        for (int bt = 0; bt < 8; ++bt)
#pragma unroll
            for (int r = 0; r < 4; ++r)
                gred[wave][bt * 16 + quad * 4 + r] = g_acc[bt][r];
    }
    __syncthreads();
    if (tid < OUT_CH)
        gs[tid] = gred[0][tid] + gred[1][tid] + gred[2][tid] + gred[3][tid];
    __syncthreads();

    // epilogue: out[n,o] = sum_{b<127} gs[b]*L2[b,o] + R[n,o] + bias[o]
    int o = tid & 127;
    int hf = tid >> 7;
    float acc = 0.f;
    int blo = hf * 64, bhi = hf ? 127 : 64;
#pragma unroll 8
    for (int b = blo; b < bhi; ++b)
        acc += gs[b] * L2[b * OUT_CH + o];   // gs[b] is an LDS broadcast (free)
    part[hf][o] = acc;
    __syncthreads();
    if (tid < 128)
        out[(size_t)n * OUT_CH + tid] =
            part[0][tid] + part[1][tid] + R[(size_t)n * OUT_CH + tid] + bias[tid];
}

// ---------------------------------------------------------------------------
// Kernel C: out += adj @ P via MFMA bf16 -- atomic-free (unchanged).
// grid 128 = 64 n-tiles (16 rows) x 2 o-halves (64 cols); waves split K=1024
// into 4 x 256, reduce through padded LDS, coalesced += into out.
// ---------------------------------------------------------------------------
__global__ void adjp_kernel(const float* __restrict__ adj,
                            const short* __restrict__ PT,
                            float* __restrict__ out) {
    int blk = blockIdx.x;
    int nb = blk & 63;          // n-tile: 16 rows
    int oh = blk >> 6;          // o-half: 64 cols
    int tid = threadIdx.x;
    int wave = tid >> 6;
    int lane = tid & 63;
    int quad = lane >> 4;
    int col  = lane & 15;
    int n0 = nb * 16;
    int o0 = oh * 64;

    f32x4 acc[4];
#pragma unroll
    for (int ot = 0; ot < 4; ++ot) acc[ot] = (f32x4){0.f, 0.f, 0.f, 0.f};

    int kbase = wave * 256;     // wave-level K-split, reduced in LDS below
#pragma unroll
    for (int ks = 0; ks < 8; ++ks) {
        int k = kbase + ks * 32 + quad * 8;
        const float* ap = adj + (size_t)(n0 + col) * NN + k;
        f32x4 a0 = *(const f32x4*)ap;
        f32x4 a1 = *(const f32x4*)(ap + 4);
        bf16x8 a;
#pragma unroll
        for (int j = 0; j < 4; ++j) { a[j] = f2bf(a0[j]); a[4 + j] = f2bf(a1[j]); }
#pragma unroll
        for (int ot = 0; ot < 4; ++ot) {
            int o = o0 + ot * 16 + col;
            bf16x8 b = *(const bf16x8*)(PT + (size_t)o * NN + k);
            acc[ot] = __builtin_amdgcn_mfma_f32_16x16x32_bf16(a, b, acc[ot], 0, 0, 0);
        }
    }

    // cross-wave K-reduction through LDS (pad 64->65: quads land on distinct banks)
    __shared__ float red[4][16][65];
#pragma unroll
    for (int ot = 0; ot < 4; ++ot)
#pragma unroll
        for (int r = 0; r < 4; ++r)
            red[wave][quad * 4 + r][ot * 16 + col] = acc[ot][r];
    __syncthreads();

    // 1024 tile elements / 256 threads = 4 each; coalesced += into out
#pragma unroll
    for (int i = tid; i < 16 * 64; i += 256) {
        int rr = i >> 6;
        int cc = i & 63;
        float v = red[0][rr][cc] + red[1][rr][cc] + red[2][rr][cc] + red[3][rr][cc];
        out[(size_t)(n0 + rr) * OUT_CH + o0 + cc] += v;
    }
}

extern "C" void kernel_launch(void* const* d_in, const int* in_sizes, int n_in,
                              void* d_out, int out_size, void* d_ws, size_t ws_size,
                              hipStream_t stream) {
    const float* node_mat    = (const float*)d_in[0];
    const float* adj         = (const float*)d_in[1];
    const float* edge_adj    = (const float*)d_in[2];
    const float* node_weight = (const float*)d_in[3];
    const float* edge_lay_1  = (const float*)d_in[4];
    const float* edge_lay_2  = (const float*)d_in[5];
    const float* root        = (const float*)d_in[6];
    const float* bias        = (const float*)d_in[7];
    float* out = (float*)d_out;

    short* PT = (short*)d_ws;                       // 128*1024 bf16 = 256 KB
    float* R  = (float*)((char*)d_ws + OUT_CH * NN * sizeof(short));  // 512 KB

    node_gemm_kernel<<<NN / 2, 256, 0, stream>>>(node_mat, node_weight, root, PT, R);
    edge_out_kernel<<<NN, 256, 0, stream>>>(edge_adj, adj, edge_lay_1, edge_lay_2,
                                            R, bias, out);
    adjp_kernel<<<128, 256, 0, stream>>>(adj, PT, out);
}